// Round 8
// baseline (701.412 us; speedup 1.0000x reference)
//
#include <hip/hip_runtime.h>
#include <hip/hip_bf16.h>

#define NW_ 192      // windows per batch item (3*8*8)
#define NWIN 384     // total windows (B * NW_)
#define NTOK 128     // tokens per window
#define CC 192
#define NHD 8
#define HD 24
#define QKVC 576
#define NROWS 49152  // NWIN * NTOK  == B*D*H*W
#define HIDN 384
#define SCALE_Q 0.20412414523193154f  // 24^-0.5

typedef __hip_bfloat16 bf16;
typedef __attribute__((ext_vector_type(8))) short s16x8;
typedef __attribute__((ext_vector_type(4))) float f32x4;

__device__ __forceinline__ float waveRedSum(float v) {
    v += __shfl_xor(v, 32);
    v += __shfl_xor(v, 16);
    v += __shfl_xor(v, 8);
    v += __shfl_xor(v, 4);
    v += __shfl_xor(v, 2);
    v += __shfl_xor(v, 1);
    return v;
}

// decode flat window-row r -> source/destination index in x (B,D,H,W,C)
__device__ __forceinline__ size_t row_to_x(int r) {
    int wb = r >> 7;
    int n = r & 127;
    int b = wb / NW_;
    int rem = wb % NW_;
    int wd = rem >> 6;
    int wh = (rem >> 3) & 7;
    int ww = rem & 7;
    int id = n >> 6;
    int ih = (n >> 3) & 7;
    int iw = n & 7;
    int d = (wd * 2 + id + 1) % 6;
    int h = (wh * 8 + ih + 4) & 63;
    int w = (ww * 8 + iw + 4) & 63;
    return ((size_t)((b * 6 + d) * 64 + h) * 64 + w) * CC;
}

__device__ __forceinline__ void split_store(float v, bf16* hi, bf16* lo) {
    bf16 h = __float2bfloat16(v);
    *hi = h;
    *lo = __float2bfloat16(v - __bfloat162float(h));
}

__global__ void zero_counts(int* counts) {
    if (threadIdx.x < 8) counts[threadIdx.x] = 0;
}

// fp32 [K][N] (optionally batched over z) -> bf16 hi/lo [N][K] transpose
__global__ __launch_bounds__(256) void transpose_w(
    const float* __restrict__ in, bf16* __restrict__ out_hi,
    bf16* __restrict__ out_lo, int K, int N) {
    size_t total = (size_t)K * N;
    in += (size_t)blockIdx.z * total;
    out_hi += (size_t)blockIdx.z * total;
    int t = blockIdx.x * 256 + threadIdx.x;
    if (t >= (int)total) return;
    int n = t / K, k = t % K;
    float v = in[(size_t)k * N + n];
    bf16 h = __float2bfloat16(v);
    out_hi[t] = h;
    if (out_lo) {
        out_lo += (size_t)blockIdx.z * total;
        out_lo[t] = __float2bfloat16(v - __bfloat162float(h));
    }
}

// expand rel-pos bias table to rpbx[head][q][k]  (8*128*128 fp32)
__global__ __launch_bounds__(256) void build_rpbx(
    const float* __restrict__ rpb, float* __restrict__ rpbx) {
    int idx = blockIdx.x * 256 + threadIdx.x;  // q*128 + k
    int q = idx >> 7, k = idx & 127;
    int dn = q >> 6, hn = (q >> 3) & 7, wn = q & 7;
    int dm = k >> 6, hm = (k >> 3) & 7, wm = k & 7;
    int ridx = (dn - dm + 1) * 225 + (hn - hm + 7) * 15 + (wn - wm + 7);
#pragma unroll
    for (int h = 0; h < 8; ++h)
        rpbx[h * 16384 + idx] = rpb[ridx * 8 + h];
}

// LN1 + roll(-SS) + window partition -> bf16 hi/lo.  4 rows/block, wave/row.
__global__ __launch_bounds__(256) void ln1_partition(
    const float* __restrict__ x, const float* __restrict__ n1w,
    const float* __restrict__ n1b, bf16* __restrict__ xw_hi,
    bf16* __restrict__ xw_lo) {
    int r = blockIdx.x * 4 + (threadIdx.x >> 6);
    int t = threadIdx.x & 63;
    const float* src = x + row_to_x(r);
    float v0 = src[t], v1 = src[t + 64], v2 = src[t + 128];
    float mu = waveRedSum(v0 + v1 + v2) * (1.0f / 192.0f);
    float d0 = v0 - mu, d1 = v1 - mu, d2 = v2 - mu;
    float var = waveRedSum(d0 * d0 + d1 * d1 + d2 * d2) * (1.0f / 192.0f);
    float rstd = rsqrtf(var + 1e-5f);
    size_t b = (size_t)r * CC;
    split_store(d0 * rstd * n1w[t]       + n1b[t],       xw_hi + b + t,       xw_lo + b + t);
    split_store(d1 * rstd * n1w[t + 64]  + n1b[t + 64],  xw_hi + b + t + 64,  xw_lo + b + t + 64);
    split_store(d2 * rstd * n1w[t + 128] + n1b[t + 128], xw_hi + b + t + 128, xw_lo + b + t + 128);
}

// xw += tiled sine positional encoding (computed analytically), hi/lo in place
__global__ __launch_bounds__(256) void add_posbias(
    bf16* __restrict__ hi, bf16* __restrict__ lo) {
    int idx = blockIdx.x * 256 + threadIdx.x;
    if (idx >= NROWS * CC) return;
    int c = idx % CC;
    int r = idx / CC;
    int n = r & 127;
    int tkn = n & 63;
    int h = tkn >> 3, w = tkn & 7;
    const float twopi_over = 6.283185307179586f / (8.0f + 1e-6f);
    float coord = (c < 96) ? (h + 1) * twopi_over : (w + 1) * twopi_over;
    int cc = (c < 96) ? c : c - 96;
    int j = cc >> 1;
    float v = coord * __expf(-0.1918820910968785f * (float)j); // ln(10000)/48
    float pe = (cc & 1) ? __cosf(v) : __sinf(v);
    float val = __bfloat162float(hi[idx]) + __bfloat162float(lo[idx]) + pe;
    split_store(val, hi + idx, lo + idx);
}

// ---------------------------------------------------------------------------
// Unified bf16 MFMA GEMM.  C[M,N] = A[M,K] @ W[K,N] (+bias, epilogue variants)
// Tile: BM=128, BN=64, BK=64.  256 threads = 4 waves in 2x2; wave (wvm,wvn)
// owns rows wvm*64..+64 (4 m-frags) x cols wvn*32..+32 (2 n-frags).
// SPLIT: A/W each given as hi+lo bf16; acc = ah*wh + ah*wl + al*wh (~fp32).
// EPI: 0 plain fp32+bias | 1 proj scatter+residual | 2 gelu->bf16 H | 3 moe2
//      weighted atomicAdd scatter | 4 qkv split-packed PER-HEAD (q scaled).
// ---------------------------------------------------------------------------
template <int EPI, int GSHIFT, bool GATHER, bool SPLIT>
__global__ __launch_bounds__(256) void mgemm(
    const bf16* __restrict__ A, const bf16* __restrict__ Alo, int ldA,
    const bf16* __restrict__ Wt, const bf16* __restrict__ Wtlo, int wStrideE,
    const float* __restrict__ bias, int biasStrideE,
    float* __restrict__ Cf, bf16* __restrict__ Cb,
    int M, int K, int N,
    const int* __restrict__ counts, const int* __restrict__ lists,
    const float* __restrict__ wts, const float* __restrict__ xres) {
    int e = blockIdx.z;
    int Mq = counts ? counts[e] : M;
    int bm = blockIdx.x * 128;
    if (bm >= Mq) return;
    int bn = blockIdx.y * 64;
    const int lbase = e * NROWS;
    __shared__ __align__(16) bf16 As[128][72];
    __shared__ __align__(16) bf16 Bs[64][72];
    __shared__ __align__(16) bf16 Asl[(SPLIT ? 128 : 1)][72];
    __shared__ __align__(16) bf16 Bsl[(SPLIT ? 64 : 1)][72];
    int t = threadIdx.x;
    // A staging map: thread t -> row t>>1, cols (t&1)*32 + {0,8,16,24}
    int arow = t >> 1, acol = (t & 1) * 32;
    // B staging map: thread t -> row t>>2, cols (t&3)*16 + {0,8}
    int brow = t >> 2, bcol = (t & 3) * 16;
    size_t aoff;
    if (GATHER) {
        int p = bm + arow;
        int a = lists[lbase + (p < Mq ? p : 0)];
        aoff = (size_t)(a >> GSHIFT) * (size_t)ldA + acol;
    } else {
        aoff = (size_t)(bm + arow) * (size_t)ldA + acol;
    }
    size_t boff = (size_t)e * wStrideE + (size_t)(bn + brow) * K + bcol;
    int wv = t >> 6, l = t & 63;
    int wvm = wv >> 1, wvn = wv & 1;
    int fr = l & 15, fg = l >> 4;
    f32x4 acc[4][2];
#pragma unroll
    for (int mf = 0; mf < 4; ++mf)
#pragma unroll
        for (int nf = 0; nf < 2; ++nf) acc[mf][nf] = (f32x4){0.f, 0.f, 0.f, 0.f};
    for (int k0 = 0; k0 < K; k0 += 64) {
        __syncthreads();
#pragma unroll
        for (int u = 0; u < 4; ++u)
            *(int4*)&As[arow][acol + u * 8] = *(const int4*)(A + aoff + k0 + u * 8);
        *(int4*)&Bs[brow][bcol]     = *(const int4*)(Wt + boff + k0);
        *(int4*)&Bs[brow][bcol + 8] = *(const int4*)(Wt + boff + k0 + 8);
        if (SPLIT) {
#pragma unroll
            for (int u = 0; u < 4; ++u)
                *(int4*)&Asl[arow][acol + u * 8] = *(const int4*)(Alo + aoff + k0 + u * 8);
            *(int4*)&Bsl[brow][bcol]     = *(const int4*)(Wtlo + boff + k0);
            *(int4*)&Bsl[brow][bcol + 8] = *(const int4*)(Wtlo + boff + k0 + 8);
        }
        __syncthreads();
#pragma unroll
        for (int ks = 0; ks < 2; ++ks) {
            s16x8 ah[4], al[4], bh[2], bl[2];
#pragma unroll
            for (int mf = 0; mf < 4; ++mf) {
                ah[mf] = *(const s16x8*)&As[wvm * 64 + mf * 16 + fr][ks * 32 + fg * 8];
                if (SPLIT) al[mf] = *(const s16x8*)&Asl[wvm * 64 + mf * 16 + fr][ks * 32 + fg * 8];
            }
#pragma unroll
            for (int nf = 0; nf < 2; ++nf) {
                bh[nf] = *(const s16x8*)&Bs[wvn * 32 + nf * 16 + fr][ks * 32 + fg * 8];
                if (SPLIT) bl[nf] = *(const s16x8*)&Bsl[wvn * 32 + nf * 16 + fr][ks * 32 + fg * 8];
            }
#pragma unroll
            for (int mf = 0; mf < 4; ++mf)
#pragma unroll
                for (int nf = 0; nf < 2; ++nf) {
                    acc[mf][nf] = __builtin_amdgcn_mfma_f32_16x16x32_bf16(ah[mf], bh[nf], acc[mf][nf], 0, 0, 0);
                    if (SPLIT) {
                        acc[mf][nf] = __builtin_amdgcn_mfma_f32_16x16x32_bf16(ah[mf], bl[nf], acc[mf][nf], 0, 0, 0);
                        acc[mf][nf] = __builtin_amdgcn_mfma_f32_16x16x32_bf16(al[mf], bh[nf], acc[mf][nf], 0, 0, 0);
                    }
                }
        }
    }
#pragma unroll
    for (int mf = 0; mf < 4; ++mf) {
        int row0 = bm + wvm * 64 + mf * 16 + fg * 4;
        if (EPI == 0) {
#pragma unroll
            for (int nf = 0; nf < 2; ++nf) {
                int c = bn + wvn * 32 + nf * 16 + fr;
                float bv = bias[c];
#pragma unroll
                for (int i = 0; i < 4; ++i)
                    Cf[(size_t)(row0 + i) * N + c] = acc[mf][nf][i] + bv;
            }
        } else if (EPI == 1) {
            size_t sr[4];
#pragma unroll
            for (int i = 0; i < 4; ++i) sr[i] = row_to_x(row0 + i);
#pragma unroll
            for (int nf = 0; nf < 2; ++nf) {
                int c = bn + wvn * 32 + nf * 16 + fr;
                float bv = bias[c];
#pragma unroll
                for (int i = 0; i < 4; ++i)
                    Cf[sr[i] + c] = xres[sr[i] + c] + acc[mf][nf][i] + bv;
            }
        } else if (EPI == 2) {
            const float* bp = bias + (size_t)e * biasStrideE;
#pragma unroll
            for (int i = 0; i < 4; ++i) {
                int p = row0 + i;
                if (p < Mq) {
                    int a = lists[lbase + p];
#pragma unroll
                    for (int nf = 0; nf < 2; ++nf) {
                        int c = bn + wvn * 32 + nf * 16 + fr;
                        float v = acc[mf][nf][i] + bp[c];
                        float g = 0.5f * v * (1.0f + erff(v * 0.7071067811865476f));
                        Cb[(size_t)a * HIDN + c] = __float2bfloat16(g);
                    }
                }
            }
        } else if (EPI == 3) {
            const float* bp = bias + (size_t)e * biasStrideE;
#pragma unroll
            for (int i = 0; i < 4; ++i) {
                int p = row0 + i;
                if (p < Mq) {
                    int a = lists[lbase + p];
                    int r = a >> 1;
                    float w = wts[lbase + p];
#pragma unroll
                    for (int nf = 0; nf < 2; ++nf) {
                        int c = bn + wvn * 32 + nf * 16 + fr;
                        atomicAdd(&Cf[(size_t)r * CC + c], w * (acc[mf][nf][i] + bp[c]));
                    }
                }
            }
        } else {  // EPI == 4: qkv epilogue -> per-head packed split q/k/v (q scaled)
            const size_t S0 = (size_t)NROWS * 192;
            const size_t S1 = (size_t)NROWS * 24;
#pragma unroll
            for (int nf = 0; nf < 2; ++nf) {
                int c = bn + wvn * 32 + nf * 16 + fr;
                int which = c / 192;
                int rem = c - which * 192;
                int hh = rem / 24;
                int d = rem - hh * 24;
                float bv = bias[c];
                bf16* hb = Cb + (size_t)(2 * which) * S0 + (size_t)hh * S1;
                bf16* lb = Cb + (size_t)(2 * which + 1) * S0 + (size_t)hh * S1;
#pragma unroll
                for (int i = 0; i < 4; ++i) {
                    float v = acc[mf][nf][i] + bv;
                    if (which == 0) v *= SCALE_Q;
                    size_t o = (size_t)(row0 + i) * 24 + d;
                    split_store(v, hb + o, lb + o);
                }
            }
        }
    }
}

// ---------------------------------------------------------------------------
// MFMA flash attention per (window, head[, half]).  Per-head qkv layout:
// tensor base + hh*NROWS*24 + row*24 + d  (fully coalesced fragment loads).
// ---------------------------------------------------------------------------
template <bool SELF>
__global__ __launch_bounds__(256) void attn_mfma(
    const bf16* __restrict__ qkvp, const float* __restrict__ mask,
    const float* __restrict__ rpbx, bf16* __restrict__ cat_hi,
    bf16* __restrict__ cat_lo) {
    constexpr int NT = SELF ? 128 : 64;   // tokens per side
    constexpr int KT = NT / 16;           // k row-tiles
    constexpr int CPW = NT / 64;          // q col-tiles per wave
    constexpr int KS = NT / 32;           // PV k-steps
    const size_t S0 = (size_t)NROWS * 192;
    const size_t S1 = (size_t)NROWS * 24;

    int wb = blockIdx.x, hh = blockIdx.y;
    int hf = SELF ? 0 : blockIdx.z;
    int qbase = wb * NTOK + (SELF ? 0 : (hf ? 0 : 64));
    int kvbase = wb * NTOK + (SELF ? 0 : (hf ? 64 : 0));
    int t = threadIdx.x;
    int wv = t >> 6, l = t & 63, fr = l & 15, fg = l >> 4;

    __shared__ __align__(16) ushort Vth[32][144];
    __shared__ __align__(16) ushort Vtl[32][144];
    __shared__ float linv_s[NT];

    // ---- stage V^T into LDS (rows 0..23 valid) ----
    {
        constexpr int PPT = 256 / NT;
        constexpr int DP = 24 / PPT;
        int tok = t % NT;
        int part = t / NT;
        const ushort* vh = (const ushort*)(qkvp + 4 * S0) + hh * S1 +
                           (size_t)(kvbase + tok) * 24 + part * DP;
        const ushort* vl = (const ushort*)(qkvp + 5 * S0) + hh * S1 +
                           (size_t)(kvbase + tok) * 24 + part * DP;
#pragma unroll
        for (int u = 0; u < DP; ++u) {
            Vth[part * DP + u][tok] = vh[u];
            Vtl[part * DP + u][tok] = vl[u];
        }
    }

    // ---- S^T = K Q^T (split) ----
    s16x8 zf = {0, 0, 0, 0, 0, 0, 0, 0};
    f32x4 st[KT][CPW];
#pragma unroll
    for (int kt = 0; kt < KT; ++kt)
#pragma unroll
        for (int c = 0; c < CPW; ++c) st[kt][c] = (f32x4){0.f, 0.f, 0.f, 0.f};

    s16x8 qfh[CPW], qfl[CPW];
#pragma unroll
    for (int c = 0; c < CPW; ++c) {
        int qt = wv * CPW + c;
        const bf16* qrow = qkvp + hh * S1 + (size_t)(qbase + qt * 16 + fr) * 24 + fg * 8;
        qfh[c] = (fg < 3) ? *(const s16x8*)qrow : zf;
        qfl[c] = (fg < 3) ? *(const s16x8*)(qrow + S0) : zf;
    }
#pragma unroll
    for (int kt = 0; kt < KT; ++kt) {
        const bf16* krow = qkvp + 2 * S0 + hh * S1 + (size_t)(kvbase + kt * 16 + fr) * 24 + fg * 8;
        s16x8 kh = (fg < 3) ? *(const s16x8*)krow : zf;
        s16x8 kl = (fg < 3) ? *(const s16x8*)(krow + S0) : zf;
#pragma unroll
        for (int c = 0; c < CPW; ++c) {
            st[kt][c] = __builtin_amdgcn_mfma_f32_16x16x32_bf16(kh, qfh[c], st[kt][c], 0, 0, 0);
            st[kt][c] = __builtin_amdgcn_mfma_f32_16x16x32_bf16(kh, qfl[c], st[kt][c], 0, 0, 0);
            st[kt][c] = __builtin_amdgcn_mfma_f32_16x16x32_bf16(kl, qfh[c], st[kt][c], 0, 0, 0);
        }
    }

    // ---- bias/mask + softmax (k-reduction: in-lane + shfl over fg) ----
    uint phq[KT][CPW][2], plq[KT][CPW][2];
#pragma unroll
    for (int c = 0; c < CPW; ++c) {
        int q = (wv * CPW + c) * 16 + fr;  // local q index
        const float* mrow = mask + ((size_t)(wb % NW_) * NTOK + q) * NTOK;
        const float* brow = rpbx + ((size_t)hh * NTOK + q) * NTOK;
        float mx = -1e30f;
#pragma unroll
        for (int kt = 0; kt < KT; ++kt) {
            int k0 = kt * 16 + fg * 4;
            float4 mk = *(const float4*)(mrow + k0);
            if (SELF) {
                float4 bs = *(const float4*)(brow + k0);
                mk.x += bs.x; mk.y += bs.y; mk.z += bs.z; mk.w += bs.w;
            }
            st[kt][c][0] += mk.x; st[kt][c][1] += mk.y;
            st[kt][c][2] += mk.z; st[kt][c][3] += mk.w;
#pragma unroll
            for (int i = 0; i < 4; ++i) mx = fmaxf(mx, st[kt][c][i]);
        }
        mx = fmaxf(mx, __shfl_xor(mx, 16));
        mx = fmaxf(mx, __shfl_xor(mx, 32));
        float ls = 0.f;
#pragma unroll
        for (int kt = 0; kt < KT; ++kt)
#pragma unroll
            for (int i = 0; i < 4; ++i) {
                float pv = __expf(st[kt][c][i] - mx);
                st[kt][c][i] = pv;
                ls += pv;
            }
        ls += __shfl_xor(ls, 16);
        ls += __shfl_xor(ls, 32);
        if (fg == 0) linv_s[q] = 1.0f / ls;
        // pack P -> split bf16 dwords (i-pairs)
#pragma unroll
        for (int kt = 0; kt < KT; ++kt) {
            ushort hb[4], lb[4];
#pragma unroll
            for (int i = 0; i < 4; ++i) {
                float pv = st[kt][c][i];
                bf16 ph = __float2bfloat16(pv);
                hb[i] = *(ushort*)&ph;
                bf16 pl = __float2bfloat16(pv - __bfloat162float(ph));
                lb[i] = *(ushort*)&pl;
            }
            phq[kt][c][0] = (uint)hb[0] | ((uint)hb[1] << 16);
            phq[kt][c][1] = (uint)hb[2] | ((uint)hb[3] << 16);
            plq[kt][c][0] = (uint)lb[0] | ((uint)lb[1] << 16);
            plq[kt][c][1] = (uint)lb[2] | ((uint)lb[3] << 16);
        }
    }
    __syncthreads();

    // ---- O = P V  (A = routed P fragments, B = LDS V^T) ----
    f32x4 oacc[CPW][2];
#pragma unroll
    for (int rt = 0; rt < CPW; ++rt)
#pragma unroll
        for (int ct = 0; ct < 2; ++ct) oacc[rt][ct] = (f32x4){0.f, 0.f, 0.f, 0.f};

    int sA = fr + 32 * (fg & 1);
    int sB = sA + 16;
    bool tsel = fg >= 2;
#pragma unroll
    for (int ks = 0; ks < KS; ++ks) {
        s16x8 bh[2], bl[2];
#pragma unroll
        for (int ct = 0; ct < 2; ++ct) {
            bh[ct] = *(const s16x8*)&Vth[ct * 16 + fr][ks * 32 + fg * 8];
            bl[ct] = *(const s16x8*)&Vtl[ct * 16 + fr][ks * 32 + fg * 8];
        }
#pragma unroll
        for (int rt = 0; rt < CPW; ++rt) {
            union { uint u[4]; s16x8 v; } ah, al;
            uint x0, x1;
            x0 = __shfl(phq[2 * ks][rt][0], sA); x1 = __shfl(phq[2 * ks + 1][rt][0], sA);
            ah.u[0] = tsel ? x1 : x0;
            x0 = __shfl(phq[2 * ks][rt][1], sA); x1 = __shfl(phq[2 * ks + 1][rt][1], sA);
            ah.u[1] = tsel ? x1 : x0;
            x0 = __shfl(phq[2 * ks][rt][0], sB); x1 = __shfl(phq[2 * ks + 1][rt][0], sB);
            ah.u[2] = tsel ? x1 : x0;
            x0 = __shfl(phq[2 * ks][rt][1], sB); x1 = __shfl(phq[2 * ks + 1][rt][1], sB);
            ah.u[3] = tsel ? x1 : x0;
            x0 = __shfl(plq[2 * ks][rt][0], sA); x1 = __shfl(plq[2 * ks + 1][rt][0], sA);
            al.u[0] = tsel ? x1 : x0;
            x0 = __shfl(plq[2 * ks][rt][1], sA); x1 = __shfl(plq[2 * ks + 1][rt][1], sA);
            al.u[1] = tsel ? x1 : x0;
            x0 = __shfl(plq[2 * ks][rt][0], sB); x1 = __shfl(plq[2 * ks + 1][rt][0], sB);
            al.u[2] = tsel ? x1 : x0;
            x0 = __shfl(plq[2 * ks][rt][1], sB); x1 = __shfl(plq[2 * ks + 1][rt][1], sB);
            al.u[3] = tsel ? x1 : x0;
#pragma unroll
            for (int ct = 0; ct < 2; ++ct) {
                oacc[rt][ct] = __builtin_amdgcn_mfma_f32_16x16x32_bf16(ah.v, bh[ct], oacc[rt][ct], 0, 0, 0);
                oacc[rt][ct] = __builtin_amdgcn_mfma_f32_16x16x32_bf16(ah.v, bl[ct], oacc[rt][ct], 0, 0, 0);
                oacc[rt][ct] = __builtin_amdgcn_mfma_f32_16x16x32_bf16(al.v, bh[ct], oacc[rt][ct], 0, 0, 0);
            }
        }
    }

    // ---- epilogue: normalize + split store to cat ----
#pragma unroll
    for (int rt = 0; rt < CPW; ++rt)
#pragma unroll
        for (int ct = 0; ct < 2; ++ct) {
            int d = ct * 16 + fr;
            if (d < 24) {
#pragma unroll
                for (int i = 0; i < 4; ++i) {
                    int q = (wv * CPW + rt) * 16 + fg * 4 + i;
                    float val = oacc[rt][ct][i] * linv_s[q];
                    int otok = SELF ? q : (hf ? 64 + q : q);
                    size_t ob = (size_t)(wb * NTOK + otok) * 384 + (SELF ? 192 : 0) + hh * 24 + d;
                    split_store(val, cat_hi + ob, cat_lo + ob);
                }
            }
        }
}

// LN2 + gate logits + top-2 select.  NO atomics: writes per-row expert pair
// and weights.  4 rows/block, one wave per row.
__global__ __launch_bounds__(256) void ln2_gate(
    const float* __restrict__ xin, const float* __restrict__ n2w,
    const float* __restrict__ n2b, const float* __restrict__ gw,
    const float* __restrict__ gb, bf16* __restrict__ xn2,
    uchar2* __restrict__ ee, float2* __restrict__ ww) {
    __shared__ float sh[4][192];
    int wave = threadIdx.x >> 6;
    int t = threadIdx.x & 63;
    int r = blockIdx.x * 4 + wave;
    const float* src = xin + (size_t)r * CC;
    float v0 = src[t], v1 = src[t + 64], v2 = src[t + 128];
    float mu = waveRedSum(v0 + v1 + v2) * (1.0f / 192.0f);
    float d0 = v0 - mu, d1 = v1 - mu, d2 = v2 - mu;
    float var = waveRedSum(d0 * d0 + d1 * d1 + d2 * d2) * (1.0f / 192.0f);
    float rstd = rsqrtf(var + 1e-5f);
    float o0 = d0 * rstd * n2w[t] + n2b[t];
    float o1 = d1 * rstd * n2w[t + 64] + n2b[t + 64];
    float o2 = d2 * rstd * n2w[t + 128] + n2b[t + 128];
    bf16* dst = xn2 + (size_t)r * CC;
    dst[t] = __float2bfloat16(o0);
    dst[t + 64] = __float2bfloat16(o1);
    dst[t + 128] = __float2bfloat16(o2);
    sh[wave][t] = o0; sh[wave][t + 64] = o1; sh[wave][t + 128] = o2;
    __builtin_amdgcn_wave_barrier();
    int e = t & 7, ch = t >> 3;
    float part = 0.0f;
    for (int c = ch * 24; c < ch * 24 + 24; ++c) part += sh[wave][c] * gw[c * 8 + e];
    part += __shfl_xor(part, 8);
    part += __shfl_xor(part, 16);
    part += __shfl_xor(part, 32);
    float logit = part + gb[e];
    float b1v = -1e30f, b2v = -1e30f;
    int i1 = 0, i2 = 0;
    for (int qe = 0; qe < 8; ++qe) {
        float lv = __shfl(logit, qe);
        if (lv > b1v) { b2v = b1v; i2 = i1; b1v = lv; i1 = qe; }
        else if (lv > b2v) { b2v = lv; i2 = qe; }
    }
    if (t == 0) {
        float e2 = __expf(b2v - b1v);
        float inv = 1.0f / (1.0f + e2);
        ee[r] = make_uchar2((unsigned char)i1, (unsigned char)i2);
        ww[r] = make_float2(inv, e2 * inv);
    }
}

// build per-expert row lists with LDS-aggregated counters (8 global atomics/blk)
__global__ __launch_bounds__(256) void route(
    const uchar2* __restrict__ ee, const float2* __restrict__ ww,
    int* __restrict__ counts, int* __restrict__ lists, float* __restrict__ wts) {
    __shared__ int lcnt[8];
    __shared__ int lbase[8];
    int t = threadIdx.x;
    int r = blockIdx.x * 256 + t;
    if (t < 8) lcnt[t] = 0;
    __syncthreads();
    uchar2 e = ee[r];
    float2 w = ww[r];
    int p1 = atomicAdd(&lcnt[e.x], 1);
    int p2 = atomicAdd(&lcnt[e.y], 1);
    __syncthreads();
    if (t < 8) lbase[t] = atomicAdd(&counts[t], lcnt[t]);
    __syncthreads();
    int d1 = e.x * NROWS + lbase[e.x] + p1;
    int d2 = e.y * NROWS + lbase[e.y] + p2;
    lists[d1] = r * 2;
    wts[d1] = w.x;
    lists[d2] = r * 2 + 1;
    wts[d2] = w.y;
}

extern "C" void kernel_launch(void* const* d_in, const int* in_sizes, int n_in,
                              void* d_out, int out_size, void* d_ws, size_t ws_size,
                              hipStream_t stream) {
    const float* x     = (const float*)d_in[0];
    const float* mask  = (const float*)d_in[1];
    const float* n1w   = (const float*)d_in[2];
    const float* n1b   = (const float*)d_in[3];
    const float* qkvsw = (const float*)d_in[4];
    const float* qkvsb = (const float*)d_in[5];
    const float* qkvmw = (const float*)d_in[6];
    const float* qkvmb = (const float*)d_in[7];
    const float* rpb   = (const float*)d_in[8];
    const float* projw = (const float*)d_in[9];
    const float* projb = (const float*)d_in[10];
    const float* n2w   = (const float*)d_in[11];
    const float* n2b   = (const float*)d_in[12];
    const float* gw    = (const float*)d_in[13];
    const float* gb    = (const float*)d_in[14];
    const float* W1    = (const float*)d_in[15];
    const float* b1    = (const float*)d_in[16];
    const float* W2    = (const float*)d_in[17];
    const float* b2    = (const float*)d_in[18];
    float* out = (float*)d_out;
    const size_t S0 = (size_t)NROWS * 192;

    char* p = (char*)d_ws;
    bf16* xw_hi = (bf16*)p;     p += S0 * 2;                      // 18.9 MB
    bf16* xw_lo = (bf16*)p;     p += S0 * 2;                      // 18.9 MB
    bf16* qkvp = (bf16*)p;                                        // 113.2 MB: per-head q_hi,q_lo,k_hi,k_lo,v_hi,v_lo
    bf16* H = (bf16*)p;         p += S0 * 6 * 2;                  // H (75.5 MB) aliases qkvp
    bf16* cat_hi = (bf16*)p;    p += (size_t)NROWS * 384 * 2;     // 37.7 MB
    bf16* cat_lo = (bf16*)p;    p += (size_t)NROWS * 384 * 2;     // 37.7 MB
    bf16* xn2 = (bf16*)p;       p += S0 * 2;                      // 18.9 MB
    int* counts = (int*)p;      p += 32;
    int* lists = (int*)p;       p += (size_t)8 * NROWS * 4;
    float* wts = (float*)p;     p += (size_t)8 * NROWS * 4;
    uchar2* ee = (uchar2*)p;    p += (size_t)NROWS * 2;
    float2* ww = (float2*)p;    p += (size_t)NROWS * 8;
    float* rpbx = (float*)p;    p += (size_t)8 * 16384 * 4;       // 512 KB
    bf16* qkvswT_hi = (bf16*)p; p += 110592 * 2;
    bf16* qkvswT_lo = (bf16*)p; p += 110592 * 2;
    bf16* qkvmwT_hi = (bf16*)p; p += 110592 * 2;
    bf16* qkvmwT_lo = (bf16*)p; p += 110592 * 2;
    bf16* projwT_hi = (bf16*)p; p += 73728 * 2;
    bf16* projwT_lo = (bf16*)p; p += 73728 * 2;
    bf16* W1T = (bf16*)p;       p += (size_t)8 * 73728 * 2;
    bf16* W2T = (bf16*)p;       p += (size_t)8 * 73728 * 2;

    zero_counts<<<1, 64, 0, stream>>>(counts);
    build_rpbx<<<64, 256, 0, stream>>>(rpb, rpbx);
    transpose_w<<<dim3(432, 1, 1), 256, 0, stream>>>(qkvsw, qkvswT_hi, qkvswT_lo, 192, 576);
    transpose_w<<<dim3(432, 1, 1), 256, 0, stream>>>(qkvmw, qkvmwT_hi, qkvmwT_lo, 192, 576);
    transpose_w<<<dim3(288, 1, 1), 256, 0, stream>>>(projw, projwT_hi, projwT_lo, 384, 192);
    transpose_w<<<dim3(288, 1, 8), 256, 0, stream>>>(W1, W1T, nullptr, 192, 384);
    transpose_w<<<dim3(288, 1, 8), 256, 0, stream>>>(W2, W2T, nullptr, 384, 192);

    ln1_partition<<<NROWS / 4, 256, 0, stream>>>(x, n1w, n1b, xw_hi, xw_lo);
    mgemm<4, 0, false, true><<<dim3(384, 9, 1), 256, 0, stream>>>(
        xw_hi, xw_lo, CC, qkvswT_hi, qkvswT_lo, 0, qkvsb, 0, nullptr, qkvp,
        NROWS, CC, QKVC, nullptr, nullptr, nullptr, nullptr);
    attn_mfma<true><<<dim3(NWIN, NHD), 256, 0, stream>>>(qkvp, mask, rpbx, cat_hi, cat_lo);
    add_posbias<<<(NROWS * CC) / 256, 256, 0, stream>>>(xw_hi, xw_lo);
    mgemm<4, 0, false, true><<<dim3(384, 9, 1), 256, 0, stream>>>(
        xw_hi, xw_lo, CC, qkvmwT_hi, qkvmwT_lo, 0, qkvmb, 0, nullptr, qkvp,
        NROWS, CC, QKVC, nullptr, nullptr, nullptr, nullptr);
    attn_mfma<false><<<dim3(NWIN, NHD, 2), 256, 0, stream>>>(qkvp, mask, rpbx, cat_hi, cat_lo);
    mgemm<1, 0, false, true><<<dim3(384, 3, 1), 256, 0, stream>>>(
        cat_hi, cat_lo, 384, projwT_hi, projwT_lo, 0, projb, 0, out, nullptr,
        NROWS, 384, CC, nullptr, nullptr, nullptr, x);
    ln2_gate<<<NROWS / 4, 256, 0, stream>>>(out, n2w, n2b, gw, gb, xn2, ee, ww);
    route<<<NROWS / 256, 256, 0, stream>>>(ee, ww, counts, lists, wts);
    mgemm<2, 1, true, false><<<dim3(384, 6, 8), 256, 0, stream>>>(
        xn2, nullptr, CC, W1T, nullptr, 73728, b1, HIDN, nullptr, H,
        NROWS, CC, HIDN, counts, lists, nullptr, nullptr);
    mgemm<3, 0, true, false><<<dim3(384, 3, 8), 256, 0, stream>>>(
        H, nullptr, HIDN, W2T, nullptr, 73728, b2, CC, out, nullptr,
        NROWS, HIDN, CC, counts, lists, wts, nullptr);
}

// Round 9
// 678.694 us; speedup vs baseline: 1.0335x; 1.0335x over previous
//
#include <hip/hip_runtime.h>
#include <hip/hip_bf16.h>

#define NW_ 192      // windows per batch item (3*8*8)
#define NWIN 384     // total windows (B * NW_)
#define NTOK 128     // tokens per window
#define CC 192
#define NHD 8
#define HD 24
#define QKVC 576
#define NROWS 49152  // NWIN * NTOK  == B*D*H*W
#define HIDN 384
#define SCALE_Q 0.20412414523193154f  // 24^-0.5

typedef __hip_bfloat16 bf16;
typedef __attribute__((ext_vector_type(8))) short s16x8;
typedef __attribute__((ext_vector_type(4))) float f32x4;

typedef __attribute__((address_space(3))) unsigned as3u;
typedef const __attribute__((address_space(1))) unsigned as1u;

// async global->LDS 16B per lane (wave-uniform LDS base + lane*16)
__device__ __forceinline__ void gl16(const void* g, void* l) {
    __builtin_amdgcn_global_load_lds((as1u*)g, (as3u*)l, 16, 0, 0);
}

__device__ __forceinline__ float waveRedSum(float v) {
    v += __shfl_xor(v, 32);
    v += __shfl_xor(v, 16);
    v += __shfl_xor(v, 8);
    v += __shfl_xor(v, 4);
    v += __shfl_xor(v, 2);
    v += __shfl_xor(v, 1);
    return v;
}

// decode flat window-row r -> source/destination index in x (B,D,H,W,C)
__device__ __forceinline__ size_t row_to_x(int r) {
    int wb = r >> 7;
    int n = r & 127;
    int b = wb / NW_;
    int rem = wb % NW_;
    int wd = rem >> 6;
    int wh = (rem >> 3) & 7;
    int ww = rem & 7;
    int id = n >> 6;
    int ih = (n >> 3) & 7;
    int iw = n & 7;
    int d = (wd * 2 + id + 1) % 6;
    int h = (wh * 8 + ih + 4) & 63;
    int w = (ww * 8 + iw + 4) & 63;
    return ((size_t)((b * 6 + d) * 64 + h) * 64 + w) * CC;
}

__device__ __forceinline__ void split_store(float v, bf16* hi, bf16* lo) {
    bf16 h = __float2bfloat16(v);
    *hi = h;
    *lo = __float2bfloat16(v - __bfloat162float(h));
}

// fp32 [K][N] (optionally batched over z) -> bf16 hi/lo [N][K] transpose
__global__ __launch_bounds__(256) void transpose_w(
    const float* __restrict__ in, bf16* __restrict__ out_hi,
    bf16* __restrict__ out_lo, int K, int N) {
    size_t total = (size_t)K * N;
    in += (size_t)blockIdx.z * total;
    out_hi += (size_t)blockIdx.z * total;
    int t = blockIdx.x * 256 + threadIdx.x;
    if (t >= (int)total) return;
    int n = t / K, k = t % K;
    float v = in[(size_t)k * N + n];
    bf16 h = __float2bfloat16(v);
    out_hi[t] = h;
    if (out_lo) {
        out_lo += (size_t)blockIdx.z * total;
        out_lo[t] = __float2bfloat16(v - __bfloat162float(h));
    }
}

// expand rel-pos bias table to rpbx[head][q][k]  (8*128*128 fp32)
__global__ __launch_bounds__(256) void build_rpbx(
    const float* __restrict__ rpb, float* __restrict__ rpbx) {
    int idx = blockIdx.x * 256 + threadIdx.x;  // q*128 + k
    int q = idx >> 7, k = idx & 127;
    int dn = q >> 6, hn = (q >> 3) & 7, wn = q & 7;
    int dm = k >> 6, hm = (k >> 3) & 7, wm = k & 7;
    int ridx = (dn - dm + 1) * 225 + (hn - hm + 7) * 15 + (wn - wm + 7);
#pragma unroll
    for (int h = 0; h < 8; ++h)
        rpbx[h * 16384 + idx] = rpb[ridx * 8 + h];
}

// LN1 + roll(-SS) + window partition -> bf16 hi/lo.  4 rows/block, wave/row.
__global__ __launch_bounds__(256) void ln1_partition(
    const float* __restrict__ x, const float* __restrict__ n1w,
    const float* __restrict__ n1b, bf16* __restrict__ xw_hi,
    bf16* __restrict__ xw_lo) {
    int r = blockIdx.x * 4 + (threadIdx.x >> 6);
    int t = threadIdx.x & 63;
    const float* src = x + row_to_x(r);
    float v0 = src[t], v1 = src[t + 64], v2 = src[t + 128];
    float mu = waveRedSum(v0 + v1 + v2) * (1.0f / 192.0f);
    float d0 = v0 - mu, d1 = v1 - mu, d2 = v2 - mu;
    float var = waveRedSum(d0 * d0 + d1 * d1 + d2 * d2) * (1.0f / 192.0f);
    float rstd = rsqrtf(var + 1e-5f);
    size_t b = (size_t)r * CC;
    split_store(d0 * rstd * n1w[t]       + n1b[t],       xw_hi + b + t,       xw_lo + b + t);
    split_store(d1 * rstd * n1w[t + 64]  + n1b[t + 64],  xw_hi + b + t + 64,  xw_lo + b + t + 64);
    split_store(d2 * rstd * n1w[t + 128] + n1b[t + 128], xw_hi + b + t + 128, xw_lo + b + t + 128);
}

// xw += tiled sine positional encoding (computed analytically), hi/lo in place
__global__ __launch_bounds__(256) void add_posbias(
    bf16* __restrict__ hi, bf16* __restrict__ lo) {
    int idx = blockIdx.x * 256 + threadIdx.x;
    if (idx >= NROWS * CC) return;
    int c = idx % CC;
    int r = idx / CC;
    int n = r & 127;
    int tkn = n & 63;
    int h = tkn >> 3, w = tkn & 7;
    const float twopi_over = 6.283185307179586f / (8.0f + 1e-6f);
    float coord = (c < 96) ? (h + 1) * twopi_over : (w + 1) * twopi_over;
    int cc = (c < 96) ? c : c - 96;
    int j = cc >> 1;
    float v = coord * __expf(-0.1918820910968785f * (float)j); // ln(10000)/48
    float pe = (cc & 1) ? __cosf(v) : __sinf(v);
    float val = __bfloat162float(hi[idx]) + __bfloat162float(lo[idx]) + pe;
    split_store(val, hi + idx, lo + idx);
}

// ---------------------------------------------------------------------------
// Unified bf16 MFMA GEMM.  C[M,N] = A[M,K] @ W[K,N] (+bias, epilogue variants)
// Tile: BM=128, BN=64, BK=64.  4 waves in 2x2; wave (wvm,wvn) owns 64x32.
// Staging: global_load_lds width=16 into LINEAR LDS with XOR swizzle:
//   lds_byte(r,c) = r*128 + (2c ^ ((r&7)<<4));  lane l of issue j sources
//   row j*8+(l>>3), elem ((l&7)^(l>>3&7))*8 + k0  -> write lands swizzled.
//   ds_read frag at (row, ks, fg): byte row*128 + (((ks*4+fg)^(fr&7))<<4).
// SPLIT: A/W each hi+lo bf16; acc = ah*wh + ah*wl + al*wh (~fp32).
// EPI: 0 plain | 1 proj scatter+residual | 2 gelu->bf16 H | 3 moe2 atomic
//      scatter | 4 qkv split-packed PER-HEAD (q scaled).
// ---------------------------------------------------------------------------
template <int EPI, int GSHIFT, bool GATHER, bool SPLIT>
__global__ __launch_bounds__(256) void mgemm(
    const bf16* __restrict__ A, const bf16* __restrict__ Alo, int ldA,
    const bf16* __restrict__ Wt, const bf16* __restrict__ Wtlo, int wStrideE,
    const float* __restrict__ bias, int biasStrideE,
    float* __restrict__ Cf, bf16* __restrict__ Cb,
    int M, int K, int N,
    const int* __restrict__ counts, const int* __restrict__ lists,
    const float* __restrict__ wts, const float* __restrict__ xres) {
    int e = blockIdx.z;
    int Mq = counts ? counts[e] : M;
    int bm = blockIdx.x * 128;
    if (bm >= Mq) return;
    int bn = blockIdx.y * 64;
    const int lbase = e * NROWS;
    __shared__ __align__(16) char Ah[128 * 128];
    __shared__ __align__(16) char Bh[64 * 128];
    __shared__ __align__(16) char Al[SPLIT ? 128 * 128 : 16];
    __shared__ __align__(16) char Bl[SPLIT ? 64 * 128 : 16];
    int t = threadIdx.x;
    int wv = t >> 6, l = t & 63;
    int lrow = l >> 3;                       // 0..7
    int lperm = ((l & 7) ^ lrow) * 8;        // element offset in 64-elem chunk
    int wvm = wv >> 1, wvn = wv & 1;
    int fr = l & 15, fg = l >> 4;

    // per-wave staging source offsets (elements), rows fixed across K
    size_t aOff[4];
#pragma unroll
    for (int u = 0; u < 4; ++u) {
        int j = wv * 4 + u;
        int p = bm + j * 8 + lrow;
        int row;
        if (GATHER) {
            int a = lists[lbase + (p < Mq ? p : 0)];
            row = a >> GSHIFT;
        } else row = p;
        aOff[u] = (size_t)row * (size_t)ldA + lperm;
    }
    size_t bOff[2];
#pragma unroll
    for (int u = 0; u < 2; ++u) {
        int j = wv * 2 + u;
        bOff[u] = (size_t)e * wStrideE + (size_t)(bn + j * 8 + lrow) * K + lperm;
    }

    f32x4 acc[4][2];
#pragma unroll
    for (int mf = 0; mf < 4; ++mf)
#pragma unroll
        for (int nf = 0; nf < 2; ++nf) acc[mf][nf] = (f32x4){0.f, 0.f, 0.f, 0.f};

    for (int k0 = 0; k0 < K; k0 += 64) {
        __syncthreads();
#pragma unroll
        for (int u = 0; u < 4; ++u) {
            gl16(A + aOff[u] + k0, Ah + (wv * 4 + u) * 1024);
            if (SPLIT) gl16(Alo + aOff[u] + k0, Al + (wv * 4 + u) * 1024);
        }
#pragma unroll
        for (int u = 0; u < 2; ++u) {
            gl16(Wt + bOff[u] + k0, Bh + (wv * 2 + u) * 1024);
            if (SPLIT) gl16(Wtlo + bOff[u] + k0, Bl + (wv * 2 + u) * 1024);
        }
        __syncthreads();   // drains vmcnt(0): all waves' LDS writes complete
#pragma unroll
        for (int ks = 0; ks < 2; ++ks) {
            int kx = ((ks * 4 + fg) ^ (fr & 7)) << 4;
            s16x8 ah[4], al[4], bh[2], bl[2];
#pragma unroll
            for (int mf = 0; mf < 4; ++mf) {
                int rb = (wvm * 64 + mf * 16 + fr) * 128;
                ah[mf] = *(const s16x8*)(Ah + rb + kx);
                if (SPLIT) al[mf] = *(const s16x8*)(Al + rb + kx);
            }
#pragma unroll
            for (int nf = 0; nf < 2; ++nf) {
                int rb = (wvn * 32 + nf * 16 + fr) * 128;
                bh[nf] = *(const s16x8*)(Bh + rb + kx);
                if (SPLIT) bl[nf] = *(const s16x8*)(Bl + rb + kx);
            }
#pragma unroll
            for (int mf = 0; mf < 4; ++mf)
#pragma unroll
                for (int nf = 0; nf < 2; ++nf) {
                    acc[mf][nf] = __builtin_amdgcn_mfma_f32_16x16x32_bf16(ah[mf], bh[nf], acc[mf][nf], 0, 0, 0);
                    if (SPLIT) {
                        acc[mf][nf] = __builtin_amdgcn_mfma_f32_16x16x32_bf16(ah[mf], bl[nf], acc[mf][nf], 0, 0, 0);
                        acc[mf][nf] = __builtin_amdgcn_mfma_f32_16x16x32_bf16(al[mf], bh[nf], acc[mf][nf], 0, 0, 0);
                    }
                }
        }
    }
#pragma unroll
    for (int mf = 0; mf < 4; ++mf) {
        int row0 = bm + wvm * 64 + mf * 16 + fg * 4;
        if (EPI == 0) {
#pragma unroll
            for (int nf = 0; nf < 2; ++nf) {
                int c = bn + wvn * 32 + nf * 16 + fr;
                float bv = bias[c];
#pragma unroll
                for (int i = 0; i < 4; ++i)
                    Cf[(size_t)(row0 + i) * N + c] = acc[mf][nf][i] + bv;
            }
        } else if (EPI == 1) {
            size_t sr[4];
#pragma unroll
            for (int i = 0; i < 4; ++i) sr[i] = row_to_x(row0 + i);
#pragma unroll
            for (int nf = 0; nf < 2; ++nf) {
                int c = bn + wvn * 32 + nf * 16 + fr;
                float bv = bias[c];
#pragma unroll
                for (int i = 0; i < 4; ++i)
                    Cf[sr[i] + c] = xres[sr[i] + c] + acc[mf][nf][i] + bv;
            }
        } else if (EPI == 2) {
            const float* bp = bias + (size_t)e * biasStrideE;
#pragma unroll
            for (int i = 0; i < 4; ++i) {
                int p = row0 + i;
                if (p < Mq) {
                    int a = lists[lbase + p];
#pragma unroll
                    for (int nf = 0; nf < 2; ++nf) {
                        int c = bn + wvn * 32 + nf * 16 + fr;
                        float v = acc[mf][nf][i] + bp[c];
                        float g = 0.5f * v * (1.0f + erff(v * 0.7071067811865476f));
                        Cb[(size_t)a * HIDN + c] = __float2bfloat16(g);
                    }
                }
            }
        } else if (EPI == 3) {
            const float* bp = bias + (size_t)e * biasStrideE;
#pragma unroll
            for (int i = 0; i < 4; ++i) {
                int p = row0 + i;
                if (p < Mq) {
                    int a = lists[lbase + p];
                    int r = a >> 1;
                    float w = wts[lbase + p];
#pragma unroll
                    for (int nf = 0; nf < 2; ++nf) {
                        int c = bn + wvn * 32 + nf * 16 + fr;
                        atomicAdd(&Cf[(size_t)r * CC + c], w * (acc[mf][nf][i] + bp[c]));
                    }
                }
            }
        } else {  // EPI == 4: qkv epilogue -> per-head packed split q/k/v (q scaled)
            const size_t S0 = (size_t)NROWS * 192;
            const size_t S1 = (size_t)NROWS * 24;
#pragma unroll
            for (int nf = 0; nf < 2; ++nf) {
                int c = bn + wvn * 32 + nf * 16 + fr;
                int which = c / 192;
                int rem = c - which * 192;
                int hh = rem / 24;
                int d = rem - hh * 24;
                float bv = bias[c];
                bf16* hb = Cb + (size_t)(2 * which) * S0 + (size_t)hh * S1;
                bf16* lb = Cb + (size_t)(2 * which + 1) * S0 + (size_t)hh * S1;
#pragma unroll
                for (int i = 0; i < 4; ++i) {
                    float v = acc[mf][nf][i] + bv;
                    if (which == 0) v *= SCALE_Q;
                    size_t o = (size_t)(row0 + i) * 24 + d;
                    split_store(v, hb + o, lb + o);
                }
            }
        }
    }
}

// ---------------------------------------------------------------------------
// MFMA flash attention per (window, head[, half]).  Per-head qkv layout:
// tensor base + hh*NROWS*24 + row*24 + d  (fully coalesced fragment loads).
// ---------------------------------------------------------------------------
template <bool SELF>
__global__ __launch_bounds__(256) void attn_mfma(
    const bf16* __restrict__ qkvp, const float* __restrict__ mask,
    const float* __restrict__ rpbx, bf16* __restrict__ cat_hi,
    bf16* __restrict__ cat_lo) {
    constexpr int NT = SELF ? 128 : 64;   // tokens per side
    constexpr int KT = NT / 16;           // k row-tiles
    constexpr int CPW = NT / 64;          // q col-tiles per wave
    constexpr int KS = NT / 32;           // PV k-steps
    const size_t S0 = (size_t)NROWS * 192;
    const size_t S1 = (size_t)NROWS * 24;

    int wb = blockIdx.x, hh = blockIdx.y;
    int hf = SELF ? 0 : blockIdx.z;
    int qbase = wb * NTOK + (SELF ? 0 : (hf ? 0 : 64));
    int kvbase = wb * NTOK + (SELF ? 0 : (hf ? 64 : 0));
    int t = threadIdx.x;
    int wv = t >> 6, l = t & 63, fr = l & 15, fg = l >> 4;

    __shared__ __align__(16) ushort Vth[32][144];
    __shared__ __align__(16) ushort Vtl[32][144];
    __shared__ float linv_s[NT];

    // ---- stage V^T into LDS (rows 0..23 valid) ----
    {
        constexpr int PPT = 256 / NT;
        constexpr int DP = 24 / PPT;
        int tok = t % NT;
        int part = t / NT;
        const ushort* vh = (const ushort*)(qkvp + 4 * S0) + hh * S1 +
                           (size_t)(kvbase + tok) * 24 + part * DP;
        const ushort* vl = (const ushort*)(qkvp + 5 * S0) + hh * S1 +
                           (size_t)(kvbase + tok) * 24 + part * DP;
#pragma unroll
        for (int u = 0; u < DP; ++u) {
            Vth[part * DP + u][tok] = vh[u];
            Vtl[part * DP + u][tok] = vl[u];
        }
    }

    // ---- S^T = K Q^T (split) ----
    s16x8 zf = {0, 0, 0, 0, 0, 0, 0, 0};
    f32x4 st[KT][CPW];
#pragma unroll
    for (int kt = 0; kt < KT; ++kt)
#pragma unroll
        for (int c = 0; c < CPW; ++c) st[kt][c] = (f32x4){0.f, 0.f, 0.f, 0.f};

    s16x8 qfh[CPW], qfl[CPW];
#pragma unroll
    for (int c = 0; c < CPW; ++c) {
        int qt = wv * CPW + c;
        const bf16* qrow = qkvp + hh * S1 + (size_t)(qbase + qt * 16 + fr) * 24 + fg * 8;
        qfh[c] = (fg < 3) ? *(const s16x8*)qrow : zf;
        qfl[c] = (fg < 3) ? *(const s16x8*)(qrow + S0) : zf;
    }
#pragma unroll
    for (int kt = 0; kt < KT; ++kt) {
        const bf16* krow = qkvp + 2 * S0 + hh * S1 + (size_t)(kvbase + kt * 16 + fr) * 24 + fg * 8;
        s16x8 kh = (fg < 3) ? *(const s16x8*)krow : zf;
        s16x8 kl = (fg < 3) ? *(const s16x8*)(krow + S0) : zf;
#pragma unroll
        for (int c = 0; c < CPW; ++c) {
            st[kt][c] = __builtin_amdgcn_mfma_f32_16x16x32_bf16(kh, qfh[c], st[kt][c], 0, 0, 0);
            st[kt][c] = __builtin_amdgcn_mfma_f32_16x16x32_bf16(kh, qfl[c], st[kt][c], 0, 0, 0);
            st[kt][c] = __builtin_amdgcn_mfma_f32_16x16x32_bf16(kl, qfh[c], st[kt][c], 0, 0, 0);
        }
    }

    // ---- bias/mask + softmax (k-reduction: in-lane + shfl over fg) ----
    uint phq[KT][CPW][2], plq[KT][CPW][2];
#pragma unroll
    for (int c = 0; c < CPW; ++c) {
        int q = (wv * CPW + c) * 16 + fr;  // local q index
        const float* mrow = mask + ((size_t)(wb % NW_) * NTOK + q) * NTOK;
        const float* brow = rpbx + ((size_t)hh * NTOK + q) * NTOK;
        float mx = -1e30f;
#pragma unroll
        for (int kt = 0; kt < KT; ++kt) {
            int k0 = kt * 16 + fg * 4;
            float4 mk = *(const float4*)(mrow + k0);
            if (SELF) {
                float4 bs = *(const float4*)(brow + k0);
                mk.x += bs.x; mk.y += bs.y; mk.z += bs.z; mk.w += bs.w;
            }
            st[kt][c][0] += mk.x; st[kt][c][1] += mk.y;
            st[kt][c][2] += mk.z; st[kt][c][3] += mk.w;
#pragma unroll
            for (int i = 0; i < 4; ++i) mx = fmaxf(mx, st[kt][c][i]);
        }
        mx = fmaxf(mx, __shfl_xor(mx, 16));
        mx = fmaxf(mx, __shfl_xor(mx, 32));
        float ls = 0.f;
#pragma unroll
        for (int kt = 0; kt < KT; ++kt)
#pragma unroll
            for (int i = 0; i < 4; ++i) {
                float pv = __expf(st[kt][c][i] - mx);
                st[kt][c][i] = pv;
                ls += pv;
            }
        ls += __shfl_xor(ls, 16);
        ls += __shfl_xor(ls, 32);
        if (fg == 0) linv_s[q] = 1.0f / ls;
        // pack P -> split bf16 dwords (i-pairs)
#pragma unroll
        for (int kt = 0; kt < KT; ++kt) {
            ushort hb[4], lb[4];
#pragma unroll
            for (int i = 0; i < 4; ++i) {
                float pv = st[kt][c][i];
                bf16 ph = __float2bfloat16(pv);
                hb[i] = *(ushort*)&ph;
                bf16 pl = __float2bfloat16(pv - __bfloat162float(ph));
                lb[i] = *(ushort*)&pl;
            }
            phq[kt][c][0] = (uint)hb[0] | ((uint)hb[1] << 16);
            phq[kt][c][1] = (uint)hb[2] | ((uint)hb[3] << 16);
            plq[kt][c][0] = (uint)lb[0] | ((uint)lb[1] << 16);
            plq[kt][c][1] = (uint)lb[2] | ((uint)lb[3] << 16);
        }
    }
    __syncthreads();

    // ---- O = P V  (A = routed P fragments, B = LDS V^T) ----
    f32x4 oacc[CPW][2];
#pragma unroll
    for (int rt = 0; rt < CPW; ++rt)
#pragma unroll
        for (int ct = 0; ct < 2; ++ct) oacc[rt][ct] = (f32x4){0.f, 0.f, 0.f, 0.f};

    int sA = fr + 32 * (fg & 1);
    int sB = sA + 16;
    bool tsel = fg >= 2;
#pragma unroll
    for (int ks = 0; ks < KS; ++ks) {
        s16x8 bh[2], bl[2];
#pragma unroll
        for (int ct = 0; ct < 2; ++ct) {
            bh[ct] = *(const s16x8*)&Vth[ct * 16 + fr][ks * 32 + fg * 8];
            bl[ct] = *(const s16x8*)&Vtl[ct * 16 + fr][ks * 32 + fg * 8];
        }
#pragma unroll
        for (int rt = 0; rt < CPW; ++rt) {
            union { uint u[4]; s16x8 v; } ah, al;
            uint x0, x1;
            x0 = __shfl(phq[2 * ks][rt][0], sA); x1 = __shfl(phq[2 * ks + 1][rt][0], sA);
            ah.u[0] = tsel ? x1 : x0;
            x0 = __shfl(phq[2 * ks][rt][1], sA); x1 = __shfl(phq[2 * ks + 1][rt][1], sA);
            ah.u[1] = tsel ? x1 : x0;
            x0 = __shfl(phq[2 * ks][rt][0], sB); x1 = __shfl(phq[2 * ks + 1][rt][0], sB);
            ah.u[2] = tsel ? x1 : x0;
            x0 = __shfl(phq[2 * ks][rt][1], sB); x1 = __shfl(phq[2 * ks + 1][rt][1], sB);
            ah.u[3] = tsel ? x1 : x0;
            x0 = __shfl(plq[2 * ks][rt][0], sA); x1 = __shfl(plq[2 * ks + 1][rt][0], sA);
            al.u[0] = tsel ? x1 : x0;
            x0 = __shfl(plq[2 * ks][rt][1], sA); x1 = __shfl(plq[2 * ks + 1][rt][1], sA);
            al.u[1] = tsel ? x1 : x0;
            x0 = __shfl(plq[2 * ks][rt][0], sB); x1 = __shfl(plq[2 * ks + 1][rt][0], sB);
            al.u[2] = tsel ? x1 : x0;
            x0 = __shfl(plq[2 * ks][rt][1], sB); x1 = __shfl(plq[2 * ks + 1][rt][1], sB);
            al.u[3] = tsel ? x1 : x0;
#pragma unroll
            for (int ct = 0; ct < 2; ++ct) {
                oacc[rt][ct] = __builtin_amdgcn_mfma_f32_16x16x32_bf16(ah.v, bh[ct], oacc[rt][ct], 0, 0, 0);
                oacc[rt][ct] = __builtin_amdgcn_mfma_f32_16x16x32_bf16(ah.v, bl[ct], oacc[rt][ct], 0, 0, 0);
                oacc[rt][ct] = __builtin_amdgcn_mfma_f32_16x16x32_bf16(al.v, bh[ct], oacc[rt][ct], 0, 0, 0);
            }
        }
    }

    // ---- epilogue: normalize + split store to cat ----
#pragma unroll
    for (int rt = 0; rt < CPW; ++rt)
#pragma unroll
        for (int ct = 0; ct < 2; ++ct) {
            int d = ct * 16 + fr;
            if (d < 24) {
#pragma unroll
                for (int i = 0; i < 4; ++i) {
                    int q = (wv * CPW + rt) * 16 + fg * 4 + i;
                    float val = oacc[rt][ct][i] * linv_s[q];
                    int otok = SELF ? q : (hf ? 64 + q : q);
                    size_t ob = (size_t)(wb * NTOK + otok) * 384 + (SELF ? 192 : 0) + hh * 24 + d;
                    split_store(val, cat_hi + ob, cat_lo + ob);
                }
            }
        }
}

// LN2 + gate logits + top-2 select.  NO atomics: writes per-row expert pair
// and weights.  4 rows/block, one wave per row.  Block 0 zeroes counts.
__global__ __launch_bounds__(256) void ln2_gate(
    const float* __restrict__ xin, const float* __restrict__ n2w,
    const float* __restrict__ n2b, const float* __restrict__ gw,
    const float* __restrict__ gb, bf16* __restrict__ xn2,
    uchar2* __restrict__ ee, float2* __restrict__ ww, int* __restrict__ counts) {
    if (blockIdx.x == 0 && threadIdx.x < 8) counts[threadIdx.x] = 0;
    __shared__ float sh[4][192];
    int wave = threadIdx.x >> 6;
    int t = threadIdx.x & 63;
    int r = blockIdx.x * 4 + wave;
    const float* src = xin + (size_t)r * CC;
    float v0 = src[t], v1 = src[t + 64], v2 = src[t + 128];
    float mu = waveRedSum(v0 + v1 + v2) * (1.0f / 192.0f);
    float d0 = v0 - mu, d1 = v1 - mu, d2 = v2 - mu;
    float var = waveRedSum(d0 * d0 + d1 * d1 + d2 * d2) * (1.0f / 192.0f);
    float rstd = rsqrtf(var + 1e-5f);
    float o0 = d0 * rstd * n2w[t] + n2b[t];
    float o1 = d1 * rstd * n2w[t + 64] + n2b[t + 64];
    float o2 = d2 * rstd * n2w[t + 128] + n2b[t + 128];
    bf16* dst = xn2 + (size_t)r * CC;
    dst[t] = __float2bfloat16(o0);
    dst[t + 64] = __float2bfloat16(o1);
    dst[t + 128] = __float2bfloat16(o2);
    sh[wave][t] = o0; sh[wave][t + 64] = o1; sh[wave][t + 128] = o2;
    __builtin_amdgcn_wave_barrier();
    int e = t & 7, ch = t >> 3;
    float part = 0.0f;
    for (int c = ch * 24; c < ch * 24 + 24; ++c) part += sh[wave][c] * gw[c * 8 + e];
    part += __shfl_xor(part, 8);
    part += __shfl_xor(part, 16);
    part += __shfl_xor(part, 32);
    float logit = part + gb[e];
    float b1v = -1e30f, b2v = -1e30f;
    int i1 = 0, i2 = 0;
    for (int qe = 0; qe < 8; ++qe) {
        float lv = __shfl(logit, qe);
        if (lv > b1v) { b2v = b1v; i2 = i1; b1v = lv; i1 = qe; }
        else if (lv > b2v) { b2v = lv; i2 = qe; }
    }
    if (t == 0) {
        float e2 = __expf(b2v - b1v);
        float inv = 1.0f / (1.0f + e2);
        ee[r] = make_uchar2((unsigned char)i1, (unsigned char)i2);
        ww[r] = make_float2(inv, e2 * inv);
    }
}

// build per-expert row lists with LDS-aggregated counters (8 global atomics/blk)
__global__ __launch_bounds__(256) void route(
    const uchar2* __restrict__ ee, const float2* __restrict__ ww,
    int* __restrict__ counts, int* __restrict__ lists, float* __restrict__ wts) {
    __shared__ int lcnt[8];
    __shared__ int lbase[8];
    int t = threadIdx.x;
    int r = blockIdx.x * 256 + t;
    if (t < 8) lcnt[t] = 0;
    __syncthreads();
    uchar2 e = ee[r];
    float2 w = ww[r];
    int p1 = atomicAdd(&lcnt[e.x], 1);
    int p2 = atomicAdd(&lcnt[e.y], 1);
    __syncthreads();
    if (t < 8) lbase[t] = atomicAdd(&counts[t], lcnt[t]);
    __syncthreads();
    int d1 = e.x * NROWS + lbase[e.x] + p1;
    int d2 = e.y * NROWS + lbase[e.y] + p2;
    lists[d1] = r * 2;
    wts[d1] = w.x;
    lists[d2] = r * 2 + 1;
    wts[d2] = w.y;
}

extern "C" void kernel_launch(void* const* d_in, const int* in_sizes, int n_in,
                              void* d_out, int out_size, void* d_ws, size_t ws_size,
                              hipStream_t stream) {
    const float* x     = (const float*)d_in[0];
    const float* mask  = (const float*)d_in[1];
    const float* n1w   = (const float*)d_in[2];
    const float* n1b   = (const float*)d_in[3];
    const float* qkvsw = (const float*)d_in[4];
    const float* qkvsb = (const float*)d_in[5];
    const float* qkvmw = (const float*)d_in[6];
    const float* qkvmb = (const float*)d_in[7];
    const float* rpb   = (const float*)d_in[8];
    const float* projw = (const float*)d_in[9];
    const float* projb = (const float*)d_in[10];
    const float* n2w   = (const float*)d_in[11];
    const float* n2b   = (const float*)d_in[12];
    const float* gw    = (const float*)d_in[13];
    const float* gb    = (const float*)d_in[14];
    const float* W1    = (const float*)d_in[15];
    const float* b1    = (const float*)d_in[16];
    const float* W2    = (const float*)d_in[17];
    const float* b2    = (const float*)d_in[18];
    float* out = (float*)d_out;
    const size_t S0 = (size_t)NROWS * 192;

    char* p = (char*)d_ws;
    bf16* xw_hi = (bf16*)p;     p += S0 * 2;                      // 18.9 MB
    bf16* xw_lo = (bf16*)p;     p += S0 * 2;                      // 18.9 MB
    bf16* qkvp = (bf16*)p;                                        // 113.2 MB: per-head q_hi,q_lo,k_hi,k_lo,v_hi,v_lo
    bf16* H = (bf16*)p;         p += S0 * 6 * 2;                  // H (75.5 MB) aliases qkvp
    bf16* cat_hi = (bf16*)p;    p += (size_t)NROWS * 384 * 2;     // 37.7 MB
    bf16* cat_lo = (bf16*)p;    p += (size_t)NROWS * 384 * 2;     // 37.7 MB
    bf16* xn2 = (bf16*)p;       p += S0 * 2;                      // 18.9 MB
    int* counts = (int*)p;      p += 32;
    int* lists = (int*)p;       p += (size_t)8 * NROWS * 4;
    float* wts = (float*)p;     p += (size_t)8 * NROWS * 4;
    uchar2* ee = (uchar2*)p;    p += (size_t)NROWS * 2;
    float2* ww = (float2*)p;    p += (size_t)NROWS * 8;
    float* rpbx = (float*)p;    p += (size_t)8 * 16384 * 4;       // 512 KB
    bf16* qkvswT_hi = (bf16*)p; p += 110592 * 2;
    bf16* qkvswT_lo = (bf16*)p; p += 110592 * 2;
    bf16* qkvmwT_hi = (bf16*)p; p += 110592 * 2;
    bf16* qkvmwT_lo = (bf16*)p; p += 110592 * 2;
    bf16* projwT_hi = (bf16*)p; p += 73728 * 2;
    bf16* projwT_lo = (bf16*)p; p += 73728 * 2;
    bf16* W1T = (bf16*)p;       p += (size_t)8 * 73728 * 2;
    bf16* W2T = (bf16*)p;       p += (size_t)8 * 73728 * 2;

    build_rpbx<<<64, 256, 0, stream>>>(rpb, rpbx);
    transpose_w<<<dim3(432, 1, 1), 256, 0, stream>>>(qkvsw, qkvswT_hi, qkvswT_lo, 192, 576);
    transpose_w<<<dim3(432, 1, 1), 256, 0, stream>>>(qkvmw, qkvmwT_hi, qkvmwT_lo, 192, 576);
    transpose_w<<<dim3(288, 1, 1), 256, 0, stream>>>(projw, projwT_hi, projwT_lo, 384, 192);
    transpose_w<<<dim3(288, 1, 8), 256, 0, stream>>>(W1, W1T, nullptr, 192, 384);
    transpose_w<<<dim3(288, 1, 8), 256, 0, stream>>>(W2, W2T, nullptr, 384, 192);

    ln1_partition<<<NROWS / 4, 256, 0, stream>>>(x, n1w, n1b, xw_hi, xw_lo);
    mgemm<4, 0, false, true><<<dim3(384, 9, 1), 256, 0, stream>>>(
        xw_hi, xw_lo, CC, qkvswT_hi, qkvswT_lo, 0, qkvsb, 0, nullptr, qkvp,
        NROWS, CC, QKVC, nullptr, nullptr, nullptr, nullptr);
    attn_mfma<true><<<dim3(NWIN, NHD), 256, 0, stream>>>(qkvp, mask, rpbx, cat_hi, cat_lo);
    add_posbias<<<(NROWS * CC) / 256, 256, 0, stream>>>(xw_hi, xw_lo);
    mgemm<4, 0, false, true><<<dim3(384, 9, 1), 256, 0, stream>>>(
        xw_hi, xw_lo, CC, qkvmwT_hi, qkvmwT_lo, 0, qkvmb, 0, nullptr, qkvp,
        NROWS, CC, QKVC, nullptr, nullptr, nullptr, nullptr);
    attn_mfma<false><<<dim3(NWIN, NHD, 2), 256, 0, stream>>>(qkvp, mask, rpbx, cat_hi, cat_lo);
    mgemm<1, 0, false, true><<<dim3(384, 3, 1), 256, 0, stream>>>(
        cat_hi, cat_lo, 384, projwT_hi, projwT_lo, 0, projb, 0, out, nullptr,
        NROWS, 384, CC, nullptr, nullptr, nullptr, x);
    ln2_gate<<<NROWS / 4, 256, 0, stream>>>(out, n2w, n2b, gw, gb, xn2, ee, ww, counts);
    route<<<NROWS / 256, 256, 0, stream>>>(ee, ww, counts, lists, wts);
    mgemm<2, 1, true, false><<<dim3(384, 6, 8), 256, 0, stream>>>(
        xn2, nullptr, CC, W1T, nullptr, 73728, b1, HIDN, nullptr, H,
        NROWS, CC, HIDN, counts, lists, nullptr, nullptr);
    mgemm<3, 0, true, false><<<dim3(384, 3, 8), 256, 0, stream>>>(
        H, nullptr, HIDN, W2T, nullptr, 73728, b2, CC, out, nullptr,
        NROWS, HIDN, CC, counts, lists, wts, nullptr);
}